// Round 17
// baseline (82.743 us; speedup 1.0000x reference)
//
#include <hip/hip_runtime.h>
#include <hip/hip_fp16.h>
#include <math.h>

#define N_PTS   8192
#define ENC     384
#define NTHREAD 384
#define NCELL1  8
#define NCELLS  512
#define RADIUS  0.12f
#define TILE8   8
#define MAXU    496          // union cap for 8-pt chunk (expect ~290, +6sigma ~390)
#define ENTCAP  124          // MAXU/4 per group
#define NCH_SLAB 256         // chunk cap per x-slab (sum ceil(c/8) <= ~212)
#define GRID_MAIN (8 * NCH_SLAB)   // 2048

__device__ __forceinline__ void fast_sincos(float x, float& s, float& c) {
    // gfx950 v_sin/v_cos take REVOLUTIONS. rev err <= |x|*2^-24 — negligible here.
    float rev = x * 0.15915494309189535f;
    rev -= rintf(rev);
    s = __builtin_amdgcn_sinf(rev);
    c = __builtin_amdgcn_cosf(rev);
}

__device__ __forceinline__ int cell_of(float x) {
    int c = (int)(x * 8.0f);
    return min(NCELL1 - 1, max(0, c));
}

static __device__ __forceinline__ unsigned h2u(__half2 h) { union { __half2 h; unsigned u; } x; x.h = h; return x.u; }
static __device__ __forceinline__ __half2 u2h(unsigned u) { union { unsigned u; __half2 h; } x; x.u = u; return x.h; }

// ---------------- ws layout ----------------
static const size_t OFF_CSTART_I = 0;       // 520 (513 used)
static const size_t OFF_CURSOR_I = 520;     // 512
static const size_t OFF_CELLID_I = 1032;    // 8192
static const size_t OFF_DESC_I   = 9224;    // 2048
static const size_t INT_END_B    = 11272u * 4;              // 45088 (16-aligned)
static const size_t OFF_SPTS_B   = INT_END_B;               // float4[8192] = 131072
static const size_t OFF_CS_B     = OFF_SPTS_B + 131072;     // 176160 (16-aligned)
// cs: (N_PTS+1) rows x 384 half2 (c,s), SORTED order; row 8192 = zero dummy
static const size_t WS_FULL_B    = OFF_CS_B + (size_t)(N_PTS + 1) * ENC * 4;

// ---------------- K1: cellid + LDS count + scans + chunk list (1 block, 512 thr) ----------------
__global__ __launch_bounds__(512) void k_scan(const float* __restrict__ pts,
                                              int* __restrict__ cell_id,
                                              int* __restrict__ cell_start,
                                              int* __restrict__ cursor,
                                              int* __restrict__ desc) {
    __shared__ int cnt_l[512];
    __shared__ int sc[512];
    __shared__ int sch[512];
    const int t = threadIdx.x;
    cnt_l[t] = 0;
    __syncthreads();
    #pragma unroll
    for (int k = 0; k < 16; ++k) {
        int i = t + k * 512;
        int cid = (cell_of(pts[3 * i + 0]) << 6) | (cell_of(pts[3 * i + 1]) << 3)
                | cell_of(pts[3 * i + 2]);
        cell_id[i] = cid;
        atomicAdd(&cnt_l[cid], 1);
    }
    __syncthreads();
    const int c = cnt_l[t];

    // full exclusive scan of counts -> cell_start / cursor
    sc[t] = c;
    __syncthreads();
    for (int off = 1; off < 512; off <<= 1) {
        int v = (t >= off) ? sc[t - off] : 0;
        __syncthreads();
        sc[t] += v;
        __syncthreads();
    }
    cell_start[t] = sc[t] - c;
    cursor[t]     = sc[t] - c;
    if (t == 511) cell_start[NCELLS] = sc[511];   // = N_PTS

    // per-slab (64-cell segment) scan of chunk counts (8-pt chunks)
    const int nch = (c + 7) >> 3;
    sch[t] = nch;
    __syncthreads();
    for (int off = 1; off < 64; off <<= 1) {
        int v = ((t & 63) >= off) ? sch[t - off] : 0;
        __syncthreads();
        sch[t] += v;
        __syncthreads();
    }
    const int rank = sch[t] - nch;

    for (int i = t; i < GRID_MAIN; i += 512) desc[i] = -1;
    __syncthreads();
    const int slab = t >> 6;
    for (int k = 0; k < nch; ++k) {
        int pos = rank + k;
        if (pos < NCH_SLAB) desc[slab + 8 * pos] = (t << 6) | k;
    }
}

// ---------------- K2: scatter into cell-sorted order ----------------
__global__ __launch_bounds__(512) void k_scatter(const float* __restrict__ pts,
                                                 const int* __restrict__ cell_id,
                                                 int* __restrict__ cursor,
                                                 float4* __restrict__ spts) {
    int i = blockIdx.x * 512 + threadIdx.x;
    if (i >= N_PTS) return;
    int pos = atomicAdd(&cursor[cell_id[i]], 1);
    spts[pos] = make_float4(pts[3 * i + 0], pts[3 * i + 1], pts[3 * i + 2],
                            __int_as_float(i));
}

// ---------------- K3: cs[pos][d] = (cos,sin) fp16, SORTED order; 8 pts/block ----------------
__global__ __launch_bounds__(NTHREAD) void k_encode(const float4* __restrict__ spts,
                                                    const float* __restrict__ A,
                                                    __half2* __restrict__ cs) {
    const int t  = threadIdx.x;
    const int p0 = blockIdx.x * 8;
    const float a0 = A[t], a1 = A[ENC + t], a2 = A[2 * ENC + t];
    #pragma unroll
    for (int k = 0; k < 8; ++k) {
        int p = p0 + k;
        if (p > N_PTS) break;
        if (p == N_PTS) {                 // dummy zero row for padded gathers
            cs[(size_t)p * ENC + t] = __floats2half2_rn(0.f, 0.f);
            break;
        }
        float4 P = spts[p];
        float qx = __fdiv_rn(P.x, RADIUS);
        float qy = __fdiv_rn(P.y, RADIUS);
        float qz = __fdiv_rn(P.z, RADIUS);
        float pa = fmaf(qz, a2, fmaf(qy, a1, qx * a0));
        float s, c;
        fast_sincos(pa, s, c);
        cs[(size_t)p * ENC + t] = __floats2half2_rn(c, s);
    }
}

// ---------------- K4: main — one 8-point chunk per block ----------------
__global__ __launch_bounds__(NTHREAD) void k_main(const float4* __restrict__ spts,
                                                  const int* __restrict__ cell_start,
                                                  const int* __restrict__ desc_g,
                                                  const uint4* __restrict__ cs4,  // row = 96 uint4
                                                  float* __restrict__ out, int out_mode) {
    const int d = desc_g[blockIdx.x];
    if (d < 0) return;
    const int cell = d >> 6;
    const int kk   = d & 63;
    const int t = threadIdx.x, lane = t & 63, wv = t >> 6;
    const int g = t / 96, q = t - g * 96;               // group 0..3; dims 4q..4q+3

    __shared__ int    run_lo[9], run_hi[9];
    __shared__ float4 own_l[TILE8];
    __shared__ int    ne;
    __shared__ __align__(16) unsigned int ent_g[4][ENTCAP];  // entry = idx | mask<<16
    __shared__ uint4  comb_a[TILE8][96];   // [point][q] — lane-consecutive, conflict-free
    __shared__ uint4  comb_b[TILE8][96];
    __shared__ float  red2[TILE8][96];
    __shared__ float  scale_l[TILE8];

    const int o_lo = cell_start[cell];
    const int o_hi = cell_start[cell + 1];
    const int pbase = o_lo + (kk << 3);
    const int np = min(TILE8, o_hi - pbase);

    // cell-level window: 9 z-runs
    const int cx = cell >> 6, cy = (cell >> 3) & 7, cz = cell & 7;
    if (t < 9) {
        int dx = t / 3 - 1, dy = t % 3 - 1;
        int cxx = cx + dx, cyy = cy + dy;
        int lo = 0, hi = 0;
        if (cxx >= 0 && cxx <= 7 && cyy >= 0 && cyy <= 7) {
            int basec = (cxx * 8 + cyy) * 8;
            int zlo = max(cz - 1, 0), zhi = min(cz + 1, 7);
            lo = cell_start[basec + zlo];
            hi = cell_start[basec + zhi + 1];
        }
        run_lo[t] = lo; run_hi[t] = hi;
    }
    if (t == 0) ne = 0;
    if (t < TILE8) {
        int idx = pbase + t;
        own_l[t] = (idx < o_hi) ? spts[idx] : make_float4(1e9f, 1e9f, 1e9f, 0.f);
    }
    __syncthreads();
    const float4 O0 = own_l[0], O1 = own_l[1], O2 = own_l[2], O3 = own_l[3];
    const float4 O4 = own_l[4], O5 = own_l[5], O6 = own_l[6], O7 = own_l[7];

    const double R2 = (double)0.12 * (double)0.12;
    const float R2_LO = 0.0144f - 1e-6f;
    const float R2_HI = 0.0144f + 1e-6f;
    const uint4* csq = cs4 + q;

    // ---- Phase 1: union scan, 8-bit membership mask (classification == R5-R16) ----
    for (int r = wv; r < 9; r += 6) {
        const int lo = run_lo[r], hi = run_hi[r];
        for (int jb = lo; jb < hi; jb += 64) {
            int j = jb + lane;
            unsigned mk = 0;
            if (j < hi) {
                float4 Pj = spts[j];
                #define TEST(O, BIT) { \
                    float fdx = Pj.x - O.x, fdy = Pj.y - O.y, fdz = Pj.z - O.z; \
                    float d2f = fmaf(fdx, fdx, fmaf(fdy, fdy, fdz * fdz)); \
                    if (d2f < R2_LO) mk |= (BIT); \
                    else if (d2f <= R2_HI) { \
                        double ddx = (double)Pj.x - (double)O.x; \
                        double ddy = (double)Pj.y - (double)O.y; \
                        double ddz = (double)Pj.z - (double)O.z; \
                        if (ddx * ddx + ddy * ddy + ddz * ddz < R2) mk |= (BIT); \
                    } }
                TEST(O0, 1u)  TEST(O1, 2u)  TEST(O2, 4u)  TEST(O3, 8u)
                TEST(O4, 16u) TEST(O5, 32u) TEST(O6, 64u) TEST(O7, 128u)
                #undef TEST
            }
            unsigned long long mask = __ballot(mk != 0);
            if (mask) {
                int leader = __ffsll((long long)mask) - 1;
                int basep = 0;
                if (lane == leader) basep = atomicAdd(&ne, __popcll(mask));
                basep = __shfl(basep, leader);
                if (mk != 0) {
                    int pos = basep + __popcll(mask & ((1ull << lane) - 1ull));
                    if (pos < MAXU) ent_g[pos & 3][pos >> 2] = (unsigned)j | (mk << 16);
                }
            }
        }
    }
    __syncthreads();
    const int ne_p  = min(ne, MAXU);
    const int total = min((ne_p + 15) & ~15, MAXU);
    if (t < total - ne_p) {
        int pos = ne_p + t;
        ent_g[pos & 3][pos >> 2] = (unsigned)N_PTS;   // dummy row, mask 0
    }
    __syncthreads();
    const int P = total >> 2;            // entries per group (multiple of 4, <= 124)

    // ---- Phase 2: each row loaded ONCE, mask-fma'd into up to 8 points ----
    __half2 ax[TILE8][4];
    #pragma unroll
    for (int pp = 0; pp < TILE8; ++pp)
        #pragma unroll
        for (int dd = 0; dd < 4; ++dd) ax[pp][dd] = u2h(0u);

    for (int m = 0; m < P; m += 4) {
        uint4 ev = *(const uint4*)&ent_g[g][m];
        uint4 r0 = csq[(size_t)(ev.x & 0xFFFFu) * 96];
        uint4 r1 = csq[(size_t)(ev.y & 0xFFFFu) * 96];
        uint4 r2 = csq[(size_t)(ev.z & 0xFFFFu) * 96];
        uint4 r3 = csq[(size_t)(ev.w & 0xFFFFu) * 96];
        #define ACCP(PP) { \
            __half2 hh = u2h(((mk_ >> PP) & 1u) ? 0x3C003C00u : 0u); \
            ax[PP][0] = __hfma2(rx, hh, ax[PP][0]); ax[PP][1] = __hfma2(ry, hh, ax[PP][1]); \
            ax[PP][2] = __hfma2(rz, hh, ax[PP][2]); ax[PP][3] = __hfma2(rw, hh, ax[PP][3]); }
        #define ACCROW(R, MK) { \
            unsigned mk_ = (MK); \
            __half2 rx = u2h(R.x), ry = u2h(R.y), rz = u2h(R.z), rw = u2h(R.w); \
            ACCP(0) ACCP(1) ACCP(2) ACCP(3) ACCP(4) ACCP(5) ACCP(6) ACCP(7) }
        ACCROW(r0, ev.x >> 16) ACCROW(r1, ev.y >> 16)
        ACCROW(r2, ev.z >> 16) ACCROW(r3, ev.w >> 16)
        #undef ACCROW
        #undef ACCP
    }

    // ---- two-stage combine (transposed conflict-free buffers) ----
    if (g == 1) {
        #pragma unroll
        for (int pp = 0; pp < TILE8; ++pp)
            comb_a[pp][q] = make_uint4(h2u(ax[pp][0]), h2u(ax[pp][1]), h2u(ax[pp][2]), h2u(ax[pp][3]));
    } else if (g == 3) {
        #pragma unroll
        for (int pp = 0; pp < TILE8; ++pp)
            comb_b[pp][q] = make_uint4(h2u(ax[pp][0]), h2u(ax[pp][1]), h2u(ax[pp][2]), h2u(ax[pp][3]));
    }
    __syncthreads();
    if (g == 0) {
        #pragma unroll
        for (int pp = 0; pp < TILE8; ++pp) {
            uint4 v = comb_a[pp][q];
            ax[pp][0] = __hadd2(ax[pp][0], u2h(v.x)); ax[pp][1] = __hadd2(ax[pp][1], u2h(v.y));
            ax[pp][2] = __hadd2(ax[pp][2], u2h(v.z)); ax[pp][3] = __hadd2(ax[pp][3], u2h(v.w));
        }
    } else if (g == 2) {
        #pragma unroll
        for (int pp = 0; pp < TILE8; ++pp) {
            uint4 v = comb_b[pp][q];
            ax[pp][0] = __hadd2(ax[pp][0], u2h(v.x)); ax[pp][1] = __hadd2(ax[pp][1], u2h(v.y));
            ax[pp][2] = __hadd2(ax[pp][2], u2h(v.z)); ax[pp][3] = __hadd2(ax[pp][3], u2h(v.w));
        }
    }
    __syncthreads();
    if (g == 2) {
        #pragma unroll
        for (int pp = 0; pp < TILE8; ++pp)
            comb_a[pp][q] = make_uint4(h2u(ax[pp][0]), h2u(ax[pp][1]), h2u(ax[pp][2]), h2u(ax[pp][3]));
    }
    __syncthreads();
    if (g == 0) {
        #pragma unroll
        for (int pp = 0; pp < TILE8; ++pp) {
            uint4 v = comb_a[pp][q];
            ax[pp][0] = __hadd2(ax[pp][0], u2h(v.x)); ax[pp][1] = __hadd2(ax[pp][1], u2h(v.y));
            ax[pp][2] = __hadd2(ax[pp][2], u2h(v.z)); ax[pp][3] = __hadd2(ax[pp][3], u2h(v.w));
        }
        // ---- norms (phase-invariant) ----
        #pragma unroll
        for (int pp = 0; pp < TILE8; ++pp) {
            float m2 = 0.f;
            #pragma unroll
            for (int dd = 0; dd < 4; ++dd) {
                float2 f = __half22float2(ax[pp][dd]);
                m2 = fmaf(f.x, f.x, fmaf(f.y, f.y, m2));
            }
            red2[pp][q] = m2;
        }
    }
    __syncthreads();
    if (t < 256) {
        int w = t >> 6, l = t & 63;
        #pragma unroll
        for (int h = 0; h < 2; ++h) {
            int pp = w + 4 * h;
            float v = red2[pp][l] + (l < 32 ? red2[pp][64 + l] : 0.f);
            #pragma unroll
            for (int off = 32; off > 0; off >>= 1) v += __shfl_down(v, off);
            if (l == 0) scale_l[pp] = sqrtf(384.0f / v);
        }
    }
    __syncthreads();
    if (g == 0) {
        #pragma unroll
        for (int pp = 0; pp < TILE8; ++pp) {
            if (pp < np) {
                const float scl = scale_l[pp];
                uint4 ov = csq[(size_t)(pbase + pp) * 96];
                float2 o0 = __half22float2(u2h(ov.x)), o1 = __half22float2(u2h(ov.y));
                float2 o2 = __half22float2(u2h(ov.z)), o3 = __half22float2(u2h(ov.w));
                float2 g0v = __half22float2(ax[pp][0]), g1v = __half22float2(ax[pp][1]);
                float2 g2v = __half22float2(ax[pp][2]), g3v = __half22float2(ax[pp][3]);
                float re0 = (g0v.x * o0.x + g0v.y * o0.y) * scl, im0 = (g0v.y * o0.x - g0v.x * o0.y) * scl;
                float re1 = (g1v.x * o1.x + g1v.y * o1.y) * scl, im1 = (g1v.y * o1.x - g1v.x * o1.y) * scl;
                float re2 = (g2v.x * o2.x + g2v.y * o2.y) * scl, im2 = (g2v.y * o2.x - g2v.x * o2.y) * scl;
                float re3 = (g3v.x * o3.x + g3v.y * o3.y) * scl, im3 = (g3v.y * o3.x - g3v.x * o3.y) * scl;
                const int o = __float_as_int(own_l[pp].w);
                if (out_mode == 0) {
                    ((float4*)out)[(size_t)o * 96 + q] = make_float4(re0, re1, re2, re3);
                } else {
                    ((float4*)out)[(size_t)o * 192 + 2 * q + 0] = make_float4(re0, im0, re1, im1);
                    ((float4*)out)[(size_t)o * 192 + 2 * q + 1] = make_float4(re2, im2, re3, im3);
                }
            }
        }
    }
}

// ---------------- last-resort all-pairs (ws too small; effectively dead) ----------------
__global__ __launch_bounds__(NTHREAD) void vecKM_allpairs(const float* __restrict__ pts,
                                                          const float* __restrict__ A,
                                                          float* __restrict__ out, int out_mode) {
    const int i = blockIdx.x;
    const int t = threadIdx.x;
    __shared__ float nb_x[512], nb_y[512], nb_z[512];
    __shared__ int nb_cnt;
    __shared__ float red[8];
    if (t == 0) nb_cnt = 0;
    __syncthreads();
    const float xi = pts[3 * i + 0], yi = pts[3 * i + 1], zi = pts[3 * i + 2];
    const double dxi = xi, dyi = yi, dzi = zi;
    const double R2 = (double)0.12 * (double)0.12;
    const float R2_LO = 0.0144f - 1e-6f, R2_HI = 0.0144f + 1e-6f;
    const int lane = t & 63;
    for (int jb = 0; jb < N_PTS; jb += NTHREAD) {
        const int j = jb + t;
        bool isnb = false;
        float xj = 0.f, yj = 0.f, zj = 0.f;
        if (j < N_PTS) {
            xj = pts[3 * j + 0]; yj = pts[3 * j + 1]; zj = pts[3 * j + 2];
            float fdx = xj - xi, fdy = yj - yi, fdz = zj - zi;
            float d2f = fmaf(fdx, fdx, fmaf(fdy, fdy, fdz * fdz));
            if (d2f < R2_LO) isnb = true;
            else if (d2f <= R2_HI) {
                double dx = (double)xj - dxi, dy = (double)yj - dyi, dz = (double)zj - dzi;
                isnb = (dx * dx + dy * dy + dz * dz) < R2;
            }
        }
        unsigned long long mask = __ballot(isnb);
        if (mask) {
            int leader = __ffsll((long long)mask) - 1;
            int basep = 0;
            if (lane == leader) basep = atomicAdd(&nb_cnt, __popcll(mask));
            basep = __shfl(basep, leader);
            if (isnb) {
                int pos = basep + __popcll(mask & ((1ull << lane) - 1ull));
                if (pos < 512) {
                    nb_x[pos] = (xj - xi) * (1.0f / 0.12f);
                    nb_y[pos] = (yj - yi) * (1.0f / 0.12f);
                    nb_z[pos] = (zj - zi) * (1.0f / 0.12f);
                }
            }
        }
    }
    __syncthreads();
    const int nn = min(nb_cnt, 512);
    const float a0 = A[t], a1 = A[ENC + t], a2 = A[2 * ENC + t];
    float gr = 0.f, gi = 0.f;
    #pragma unroll 4
    for (int m = 0; m < nn; ++m) {
        float pa = fmaf(nb_z[m], a2, fmaf(nb_y[m], a1, nb_x[m] * a0));
        float sv, cv;
        fast_sincos(pa, sv, cv);
        gr += cv; gi += sv;
    }
    float m2 = fmaf(gr, gr, gi * gi);
    #pragma unroll
    for (int off = 32; off > 0; off >>= 1) m2 += __shfl_down(m2, off);
    const int wid = t >> 6;
    if (lane == 0) red[wid] = m2;
    __syncthreads();
    if (t == 0) {
        float tot = 0.f;
        for (int w = 0; w < NTHREAD / 64; ++w) tot += red[w];
        red[7] = tot;
    }
    __syncthreads();
    const float scale = sqrtf(384.0f / red[7]);
    const float re = gr * scale, im = gi * scale;
    if (out_mode == 0) out[i * ENC + t] = re;
    else ((float2*)out)[i * ENC + t] = make_float2(re, im);
}

extern "C" void kernel_launch(void* const* d_in, const int* in_sizes, int n_in,
                              void* d_out, int out_size, void* d_ws, size_t ws_size,
                              hipStream_t stream) {
    const float* pts = (const float*)d_in[0];
    const float* A   = (const float*)d_in[1];
    float* out = (float*)d_out;
    const int out_mode = (out_size >= 2 * N_PTS * ENC) ? 1 : 0;

    if (ws_size >= WS_FULL_B) {
        int*     cell_start = (int*)d_ws + OFF_CSTART_I;
        int*     cursor     = (int*)d_ws + OFF_CURSOR_I;
        int*     cell_id    = (int*)d_ws + OFF_CELLID_I;
        int*     desc       = (int*)d_ws + OFF_DESC_I;
        float4*  spts       = (float4*)((char*)d_ws + OFF_SPTS_B);
        __half2* cs         = (__half2*)((char*)d_ws + OFF_CS_B);

        k_scan<<<1, 512, 0, stream>>>(pts, cell_id, cell_start, cursor, desc);
        k_scatter<<<16, 512, 0, stream>>>(pts, cell_id, cursor, spts);
        k_encode<<<(N_PTS / 8) + 1, NTHREAD, 0, stream>>>(spts, A, cs);
        k_main<<<GRID_MAIN, NTHREAD, 0, stream>>>(spts, cell_start, desc,
                                                  (const uint4*)cs, out, out_mode);
    } else {
        vecKM_allpairs<<<N_PTS, NTHREAD, 0, stream>>>(pts, A, out, out_mode);
    }
}

// Round 18
// 67.538 us; speedup vs baseline: 1.2251x; 1.2251x over previous
//
#include <hip/hip_runtime.h>
#include <hip/hip_fp16.h>
#include <math.h>

#define N_PTS   8192
#define ENC     384
#define NTHREAD 384
#define NCELL1  8
#define NCELLS  512
#define RADIUS  0.12f
#define MAXU    368          // union-list cap in entries (avg ~145 for 4 pts)
#define NCH_SLAB 384         // chunk cap per x-slab
#define GRID_MAIN (8 * NCH_SLAB)   // 3072

__device__ __forceinline__ void fast_sincos(float x, float& s, float& c) {
    // gfx950 v_sin/v_cos take REVOLUTIONS. rev err <= |x|*2^-24 — negligible here.
    float rev = x * 0.15915494309189535f;
    rev -= rintf(rev);
    s = __builtin_amdgcn_sinf(rev);
    c = __builtin_amdgcn_cosf(rev);
}

__device__ __forceinline__ int cell_of(float x) {
    int c = (int)(x * 8.0f);
    return min(NCELL1 - 1, max(0, c));
}

static __device__ __forceinline__ unsigned h2u(__half2 h) { union { __half2 h; unsigned u; } x; x.h = h; return x.u; }
static __device__ __forceinline__ __half2 u2h(unsigned u) { union { unsigned u; __half2 h; } x; x.u = u; return x.h; }

// ---------------- ws layout ----------------
static const size_t OFF_CSTART_I = 0;       // 520 (513 used)
static const size_t OFF_DESC_I   = 520;     // 3072
static const size_t INT_END_B    = 3600u * 4;               // 14400 -> pad to 16
static const size_t OFF_SPTS_B   = 14400;                   // float4[8192] = 131072
static const size_t OFF_CS_B     = OFF_SPTS_B + 131072;     // 145472 (16-aligned)
// cs: (N_PTS+1) rows x 384 half2 (c,s), SORTED order; row 8192 = zero dummy
static const size_t WS_FULL_B    = OFF_CS_B + (size_t)(N_PTS + 1) * ENC * 4;

// ---------------- K1: fused cellid+count+scan+chunklist+scatter (1 block, 512 thr) ----------------
__global__ __launch_bounds__(512) void k_prep(const float* __restrict__ pts,
                                              int* __restrict__ cell_start,
                                              int* __restrict__ desc,
                                              float4* __restrict__ spts) {
    __shared__ int cnt_l[512];
    __shared__ int sc[512];
    __shared__ int sch[512];
    __shared__ int cur_l[512];
    const int t = threadIdx.x;
    cnt_l[t] = 0;
    __syncthreads();

    float xs[16], ys[16], zs[16];
    int   cids[16];
    #pragma unroll
    for (int k = 0; k < 16; ++k) {
        int i = t + k * 512;
        float x = pts[3 * i + 0], y = pts[3 * i + 1], z = pts[3 * i + 2];
        xs[k] = x; ys[k] = y; zs[k] = z;
        int cid = (cell_of(x) << 6) | (cell_of(y) << 3) | cell_of(z);
        cids[k] = cid;
        atomicAdd(&cnt_l[cid], 1);
    }
    __syncthreads();
    const int c = cnt_l[t];

    // full exclusive scan -> cell_start + LDS cursor
    sc[t] = c;
    __syncthreads();
    for (int off = 1; off < 512; off <<= 1) {
        int v = (t >= off) ? sc[t - off] : 0;
        __syncthreads();
        sc[t] += v;
        __syncthreads();
    }
    cell_start[t] = sc[t] - c;
    cur_l[t]      = sc[t] - c;
    if (t == 511) cell_start[NCELLS] = sc[511];   // = N_PTS

    // per-slab (64-cell segment) scan of chunk counts (4-pt chunks)
    const int nch = (c + 3) >> 2;
    sch[t] = nch;
    __syncthreads();
    for (int off = 1; off < 64; off <<= 1) {
        int v = ((t & 63) >= off) ? sch[t - off] : 0;
        __syncthreads();
        sch[t] += v;
        __syncthreads();
    }
    const int rank = sch[t] - nch;

    for (int i = t; i < GRID_MAIN; i += 512) desc[i] = -1;
    __syncthreads();
    const int slab = t >> 6;
    for (int k = 0; k < nch; ++k) {
        int pos = rank + k;
        if (pos < NCH_SLAB) desc[slab + 8 * pos] = (t << 6) | k;
    }

    // scatter from registers via LDS cursors
    #pragma unroll
    for (int k = 0; k < 16; ++k) {
        int i = t + k * 512;
        int pos = atomicAdd(&cur_l[cids[k]], 1);
        spts[pos] = make_float4(xs[k], ys[k], zs[k], __int_as_float(i));
    }
}

// ---------------- K2: cs[pos][d] = (cos,sin) fp16, SORTED order; 8 pts/block ----------------
__global__ __launch_bounds__(NTHREAD) void k_encode(const float4* __restrict__ spts,
                                                    const float* __restrict__ A,
                                                    __half2* __restrict__ cs) {
    const int t  = threadIdx.x;
    const int p0 = blockIdx.x * 8;
    const float a0 = A[t], a1 = A[ENC + t], a2 = A[2 * ENC + t];
    #pragma unroll
    for (int k = 0; k < 8; ++k) {
        int p = p0 + k;
        if (p > N_PTS) break;
        if (p == N_PTS) {                 // dummy zero row for padded gathers
            cs[(size_t)p * ENC + t] = __floats2half2_rn(0.f, 0.f);
            break;
        }
        float4 P = spts[p];
        float qx = __fdiv_rn(P.x, RADIUS);
        float qy = __fdiv_rn(P.y, RADIUS);
        float qz = __fdiv_rn(P.z, RADIUS);
        float pa = fmaf(qz, a2, fmaf(qy, a1, qx * a0));
        float s, c;
        fast_sincos(pa, s, c);
        cs[(size_t)p * ENC + t] = __floats2half2_rn(c, s);
    }
}

// ---------------- K4: main — one 4-point chunk per block (R16 body, unchanged) ----------------
__global__ __launch_bounds__(NTHREAD) void k_main(const float4* __restrict__ spts,
                                                  const int* __restrict__ cell_start,
                                                  const int* __restrict__ desc_g,
                                                  const uint4* __restrict__ cs4,  // row = 96 uint4
                                                  float* __restrict__ out, int out_mode) {
    const int d = desc_g[blockIdx.x];
    if (d < 0) return;
    const int cell = d >> 6;
    const int kk   = d & 63;
    const int t = threadIdx.x, lane = t & 63, wv = t >> 6;
    const int g = t / 96, q = t - g * 96;               // group 0..3; dims 4q..4q+3

    __shared__ int    run_lo[9], run_hi[9];
    __shared__ float4 own_l[4];
    __shared__ int    ne;
    __shared__ __align__(16) unsigned int ent_g[4][96];   // entry = idx | mask<<16
    __shared__ uint4  comb_a[4][96];    // [point][q] — lane-consecutive, conflict-free
    __shared__ uint4  comb_b[4][96];
    __shared__ float  red2[4][96];
    __shared__ float  scale_l[4];

    const int o_lo = cell_start[cell];
    const int o_hi = cell_start[cell + 1];
    const int pbase = o_lo + (kk << 2);
    const int np = min(4, o_hi - pbase);

    // cell-level window: 9 z-runs
    const int cx = cell >> 6, cy = (cell >> 3) & 7, cz = cell & 7;
    if (t < 9) {
        int dx = t / 3 - 1, dy = t % 3 - 1;
        int cxx = cx + dx, cyy = cy + dy;
        int lo = 0, hi = 0;
        if (cxx >= 0 && cxx <= 7 && cyy >= 0 && cyy <= 7) {
            int basec = (cxx * 8 + cyy) * 8;
            int zlo = max(cz - 1, 0), zhi = min(cz + 1, 7);
            lo = cell_start[basec + zlo];
            hi = cell_start[basec + zhi + 1];
        }
        run_lo[t] = lo; run_hi[t] = hi;
    }
    if (t == 0) ne = 0;
    if (t < 4) {
        int idx = pbase + t;
        own_l[t] = (idx < o_hi) ? spts[idx] : make_float4(1e9f, 1e9f, 1e9f, 0.f);
    }
    __syncthreads();
    const float4 O0 = own_l[0], O1 = own_l[1], O2 = own_l[2], O3 = own_l[3];

    const double R2 = (double)0.12 * (double)0.12;
    const float R2_LO = 0.0144f - 1e-6f;
    const float R2_HI = 0.0144f + 1e-6f;
    const uint4* csq = cs4 + q;

    // ---- Phase 1: union scan, 4-bit membership mask (classification == R5-R17) ----
    for (int r = wv; r < 9; r += 6) {
        const int lo = run_lo[r], hi = run_hi[r];
        for (int jb = lo; jb < hi; jb += 64) {
            int j = jb + lane;
            unsigned mk = 0;
            if (j < hi) {
                float4 Pj = spts[j];
                #define TEST(O, BIT) { \
                    float fdx = Pj.x - O.x, fdy = Pj.y - O.y, fdz = Pj.z - O.z; \
                    float d2f = fmaf(fdx, fdx, fmaf(fdy, fdy, fdz * fdz)); \
                    if (d2f < R2_LO) mk |= (BIT); \
                    else if (d2f <= R2_HI) { \
                        double ddx = (double)Pj.x - (double)O.x; \
                        double ddy = (double)Pj.y - (double)O.y; \
                        double ddz = (double)Pj.z - (double)O.z; \
                        if (ddx * ddx + ddy * ddy + ddz * ddz < R2) mk |= (BIT); \
                    } }
                TEST(O0, 1u) TEST(O1, 2u) TEST(O2, 4u) TEST(O3, 8u)
                #undef TEST
            }
            unsigned long long mask = __ballot(mk != 0);
            if (mask) {
                int leader = __ffsll((long long)mask) - 1;
                int basep = 0;
                if (lane == leader) basep = atomicAdd(&ne, __popcll(mask));
                basep = __shfl(basep, leader);
                if (mk != 0) {
                    int pos = basep + __popcll(mask & ((1ull << lane) - 1ull));
                    if (pos < MAXU) ent_g[pos & 3][pos >> 2] = (unsigned)j | (mk << 16);
                }
            }
        }
    }
    __syncthreads();
    const int ne_p  = min(ne, MAXU);
    const int total = (ne_p + 15) & ~15;
    if (t < total - ne_p) {
        int pos = ne_p + t;
        ent_g[pos & 3][pos >> 2] = (unsigned)N_PTS;   // dummy row, mask 0
    }
    __syncthreads();
    const int P = total >> 2;            // entries per group (multiple of 4, <= 92)

    // ---- Phase 2: each row loaded ONCE, mask-fma'd into up to 4 points ----
    __half2 ax0[4], ax1[4], ax2[4], ax3[4];
    #pragma unroll
    for (int dd = 0; dd < 4; ++dd) {
        ax0[dd] = u2h(0u); ax1[dd] = u2h(0u); ax2[dd] = u2h(0u); ax3[dd] = u2h(0u);
    }
    for (int m = 0; m < P; m += 4) {
        uint4 ev = *(const uint4*)&ent_g[g][m];
        uint4 r0 = csq[(size_t)(ev.x & 0xFFFFu) * 96];
        uint4 r1 = csq[(size_t)(ev.y & 0xFFFFu) * 96];
        uint4 r2 = csq[(size_t)(ev.z & 0xFFFFu) * 96];
        uint4 r3 = csq[(size_t)(ev.w & 0xFFFFu) * 96];
        #define ACC4(R, MK) { \
            unsigned mk_ = (MK); \
            __half2 h0 = u2h((mk_ & 1u) ? 0x3C003C00u : 0u); \
            __half2 h1 = u2h((mk_ & 2u) ? 0x3C003C00u : 0u); \
            __half2 h2 = u2h((mk_ & 4u) ? 0x3C003C00u : 0u); \
            __half2 h3 = u2h((mk_ & 8u) ? 0x3C003C00u : 0u); \
            __half2 rx = u2h(R.x), ry = u2h(R.y), rz = u2h(R.z), rw = u2h(R.w); \
            ax0[0] = __hfma2(rx, h0, ax0[0]); ax0[1] = __hfma2(ry, h0, ax0[1]); \
            ax0[2] = __hfma2(rz, h0, ax0[2]); ax0[3] = __hfma2(rw, h0, ax0[3]); \
            ax1[0] = __hfma2(rx, h1, ax1[0]); ax1[1] = __hfma2(ry, h1, ax1[1]); \
            ax1[2] = __hfma2(rz, h1, ax1[2]); ax1[3] = __hfma2(rw, h1, ax1[3]); \
            ax2[0] = __hfma2(rx, h2, ax2[0]); ax2[1] = __hfma2(ry, h2, ax2[1]); \
            ax2[2] = __hfma2(rz, h2, ax2[2]); ax2[3] = __hfma2(rw, h2, ax2[3]); \
            ax3[0] = __hfma2(rx, h3, ax3[0]); ax3[1] = __hfma2(ry, h3, ax3[1]); \
            ax3[2] = __hfma2(rz, h3, ax3[2]); ax3[3] = __hfma2(rw, h3, ax3[3]); }
        ACC4(r0, ev.x >> 16) ACC4(r1, ev.y >> 16) ACC4(r2, ev.z >> 16) ACC4(r3, ev.w >> 16)
        #undef ACC4
    }

    // ---- two-stage combine (transposed conflict-free buffers) ----
    #define PACK4(A) make_uint4(h2u(A[0]), h2u(A[1]), h2u(A[2]), h2u(A[3]))
    #define ADDU(A, V) { A[0] = __hadd2(A[0], u2h(V.x)); A[1] = __hadd2(A[1], u2h(V.y)); \
                         A[2] = __hadd2(A[2], u2h(V.z)); A[3] = __hadd2(A[3], u2h(V.w)); }
    if (g == 1) { comb_a[0][q] = PACK4(ax0); comb_a[1][q] = PACK4(ax1);
                  comb_a[2][q] = PACK4(ax2); comb_a[3][q] = PACK4(ax3); }
    else if (g == 3) { comb_b[0][q] = PACK4(ax0); comb_b[1][q] = PACK4(ax1);
                       comb_b[2][q] = PACK4(ax2); comb_b[3][q] = PACK4(ax3); }
    __syncthreads();
    if (g == 0) { uint4 v0 = comb_a[0][q], v1 = comb_a[1][q], v2 = comb_a[2][q], v3 = comb_a[3][q];
                  ADDU(ax0, v0) ADDU(ax1, v1) ADDU(ax2, v2) ADDU(ax3, v3) }
    else if (g == 2) { uint4 v0 = comb_b[0][q], v1 = comb_b[1][q], v2 = comb_b[2][q], v3 = comb_b[3][q];
                       ADDU(ax0, v0) ADDU(ax1, v1) ADDU(ax2, v2) ADDU(ax3, v3) }
    __syncthreads();
    if (g == 2) { comb_a[0][q] = PACK4(ax0); comb_a[1][q] = PACK4(ax1);
                  comb_a[2][q] = PACK4(ax2); comb_a[3][q] = PACK4(ax3); }
    __syncthreads();
    if (g == 0) {
        uint4 v0 = comb_a[0][q], v1 = comb_a[1][q], v2 = comb_a[2][q], v3 = comb_a[3][q];
        ADDU(ax0, v0) ADDU(ax1, v1) ADDU(ax2, v2) ADDU(ax3, v3)
        #define NORM_P(AC, PP) { float m2 = 0.f; \
            _Pragma("unroll") for (int dd = 0; dd < 4; ++dd) { \
                float2 f = __half22float2(AC[dd]); \
                m2 = fmaf(f.x, f.x, fmaf(f.y, f.y, m2)); } \
            red2[PP][q] = m2; }
        NORM_P(ax0, 0) NORM_P(ax1, 1) NORM_P(ax2, 2) NORM_P(ax3, 3)
        #undef NORM_P
    }
    #undef PACK4
    #undef ADDU
    __syncthreads();
    if (t < 256) {
        int w = t >> 6, l = t & 63;
        float v = red2[w][l] + (l < 32 ? red2[w][64 + l] : 0.f);
        #pragma unroll
        for (int off = 32; off > 0; off >>= 1) v += __shfl_down(v, off);
        if (l == 0) scale_l[w] = sqrtf(384.0f / v);
    }
    __syncthreads();
    if (g == 0) {
        #define STORE_P(AC, PP) if ((PP) < np) { \
            const float scl = scale_l[PP]; \
            uint4 ov = csq[(size_t)(pbase + (PP)) * 96]; \
            float2 o0 = __half22float2(u2h(ov.x)), o1 = __half22float2(u2h(ov.y)); \
            float2 o2 = __half22float2(u2h(ov.z)), o3 = __half22float2(u2h(ov.w)); \
            float2 g0v = __half22float2(AC[0]), g1v = __half22float2(AC[1]); \
            float2 g2v = __half22float2(AC[2]), g3v = __half22float2(AC[3]); \
            float re0 = (g0v.x * o0.x + g0v.y * o0.y) * scl, im0 = (g0v.y * o0.x - g0v.x * o0.y) * scl; \
            float re1 = (g1v.x * o1.x + g1v.y * o1.y) * scl, im1 = (g1v.y * o1.x - g1v.x * o1.y) * scl; \
            float re2 = (g2v.x * o2.x + g2v.y * o2.y) * scl, im2 = (g2v.y * o2.x - g2v.x * o2.y) * scl; \
            float re3 = (g3v.x * o3.x + g3v.y * o3.y) * scl, im3 = (g3v.y * o3.x - g3v.x * o3.y) * scl; \
            const int o = __float_as_int(own_l[PP].w); \
            if (out_mode == 0) { \
                ((float4*)out)[(size_t)o * 96 + q] = make_float4(re0, re1, re2, re3); \
            } else { \
                ((float4*)out)[(size_t)o * 192 + 2 * q + 0] = make_float4(re0, im0, re1, im1); \
                ((float4*)out)[(size_t)o * 192 + 2 * q + 1] = make_float4(re2, im2, re3, im3); \
            } }
        STORE_P(ax0, 0) STORE_P(ax1, 1) STORE_P(ax2, 2) STORE_P(ax3, 3)
        #undef STORE_P
    }
}

// ---------------- last-resort all-pairs (ws too small; effectively dead) ----------------
__global__ __launch_bounds__(NTHREAD) void vecKM_allpairs(const float* __restrict__ pts,
                                                          const float* __restrict__ A,
                                                          float* __restrict__ out, int out_mode) {
    const int i = blockIdx.x;
    const int t = threadIdx.x;
    __shared__ float nb_x[512], nb_y[512], nb_z[512];
    __shared__ int nb_cnt;
    __shared__ float red[8];
    if (t == 0) nb_cnt = 0;
    __syncthreads();
    const float xi = pts[3 * i + 0], yi = pts[3 * i + 1], zi = pts[3 * i + 2];
    const double dxi = xi, dyi = yi, dzi = zi;
    const double R2 = (double)0.12 * (double)0.12;
    const float R2_LO = 0.0144f - 1e-6f, R2_HI = 0.0144f + 1e-6f;
    const int lane = t & 63;
    for (int jb = 0; jb < N_PTS; jb += NTHREAD) {
        const int j = jb + t;
        bool isnb = false;
        float xj = 0.f, yj = 0.f, zj = 0.f;
        if (j < N_PTS) {
            xj = pts[3 * j + 0]; yj = pts[3 * j + 1]; zj = pts[3 * j + 2];
            float fdx = xj - xi, fdy = yj - yi, fdz = zj - zi;
            float d2f = fmaf(fdx, fdx, fmaf(fdy, fdy, fdz * fdz));
            if (d2f < R2_LO) isnb = true;
            else if (d2f <= R2_HI) {
                double dx = (double)xj - dxi, dy = (double)yj - dyi, dz = (double)zj - dzi;
                isnb = (dx * dx + dy * dy + dz * dz) < R2;
            }
        }
        unsigned long long mask = __ballot(isnb);
        if (mask) {
            int leader = __ffsll((long long)mask) - 1;
            int basep = 0;
            if (lane == leader) basep = atomicAdd(&nb_cnt, __popcll(mask));
            basep = __shfl(basep, leader);
            if (isnb) {
                int pos = basep + __popcll(mask & ((1ull << lane) - 1ull));
                if (pos < 512) {
                    nb_x[pos] = (xj - xi) * (1.0f / 0.12f);
                    nb_y[pos] = (yj - yi) * (1.0f / 0.12f);
                    nb_z[pos] = (zj - zi) * (1.0f / 0.12f);
                }
            }
        }
    }
    __syncthreads();
    const int nn = min(nb_cnt, 512);
    const float a0 = A[t], a1 = A[ENC + t], a2 = A[2 * ENC + t];
    float gr = 0.f, gi = 0.f;
    #pragma unroll 4
    for (int m = 0; m < nn; ++m) {
        float pa = fmaf(nb_z[m], a2, fmaf(nb_y[m], a1, nb_x[m] * a0));
        float sv, cv;
        fast_sincos(pa, sv, cv);
        gr += cv; gi += sv;
    }
    float m2 = fmaf(gr, gr, gi * gi);
    #pragma unroll
    for (int off = 32; off > 0; off >>= 1) m2 += __shfl_down(m2, off);
    const int wid = t >> 6;
    if (lane == 0) red[wid] = m2;
    __syncthreads();
    if (t == 0) {
        float tot = 0.f;
        for (int w = 0; w < NTHREAD / 64; ++w) tot += red[w];
        red[7] = tot;
    }
    __syncthreads();
    const float scale = sqrtf(384.0f / red[7]);
    const float re = gr * scale, im = gi * scale;
    if (out_mode == 0) out[i * ENC + t] = re;
    else ((float2*)out)[i * ENC + t] = make_float2(re, im);
}

extern "C" void kernel_launch(void* const* d_in, const int* in_sizes, int n_in,
                              void* d_out, int out_size, void* d_ws, size_t ws_size,
                              hipStream_t stream) {
    const float* pts = (const float*)d_in[0];
    const float* A   = (const float*)d_in[1];
    float* out = (float*)d_out;
    const int out_mode = (out_size >= 2 * N_PTS * ENC) ? 1 : 0;

    if (ws_size >= WS_FULL_B) {
        int*     cell_start = (int*)d_ws + OFF_CSTART_I;
        int*     desc       = (int*)d_ws + OFF_DESC_I;
        float4*  spts       = (float4*)((char*)d_ws + OFF_SPTS_B);
        __half2* cs         = (__half2*)((char*)d_ws + OFF_CS_B);

        k_prep<<<1, 512, 0, stream>>>(pts, cell_start, desc, spts);
        k_encode<<<(N_PTS / 8) + 1, NTHREAD, 0, stream>>>(spts, A, cs);
        k_main<<<GRID_MAIN, NTHREAD, 0, stream>>>(spts, cell_start, desc,
                                                  (const uint4*)cs, out, out_mode);
    } else {
        vecKM_allpairs<<<N_PTS, NTHREAD, 0, stream>>>(pts, A, out, out_mode);
    }
}

// Round 19
// 66.873 us; speedup vs baseline: 1.2373x; 1.0099x over previous
//
#include <hip/hip_runtime.h>
#include <hip/hip_fp16.h>
#include <math.h>

#define N_PTS   8192
#define ENC     384
#define NTHREAD 384
#define NCELL1  8
#define NCELLS  512
#define RADIUS  0.12f
#define MAXU    368          // union-list cap in entries (avg ~145 for 4 pts)
#define NCH_SLAB 384         // chunk cap per x-slab
#define GRID_MAIN (8 * NCH_SLAB)   // 3072

__device__ __forceinline__ void fast_sincos(float x, float& s, float& c) {
    // gfx950 v_sin/v_cos take REVOLUTIONS. rev err <= |x|*2^-24 — negligible here.
    float rev = x * 0.15915494309189535f;
    rev -= rintf(rev);
    s = __builtin_amdgcn_sinf(rev);
    c = __builtin_amdgcn_cosf(rev);
}

__device__ __forceinline__ int cell_of(float x) {
    int c = (int)(x * 8.0f);
    return min(NCELL1 - 1, max(0, c));
}

static __device__ __forceinline__ unsigned h2u(__half2 h) { union { __half2 h; unsigned u; } x; x.h = h; return x.u; }
static __device__ __forceinline__ __half2 u2h(unsigned u) { union { unsigned u; __half2 h; } x; x.u = u; return x.h; }

// ---------------- ws layout ----------------
static const size_t OFF_CSTART_I = 0;       // 520 (513 used)
static const size_t OFF_DESC_I   = 520;     // 3072
static const size_t INT_END_B    = 3600u * 4;               // 14400 -> pad to 16
static const size_t OFF_SPTS_B   = 14400;                   // float4[8192] = 131072
static const size_t OFF_CS_B     = OFF_SPTS_B + 131072;     // 145472 (16-aligned)
// cs: (N_PTS+1) rows x 384 half2 (c,s), SORTED order; row 8192 = zero dummy
static const size_t WS_FULL_B    = OFF_CS_B + (size_t)(N_PTS + 1) * ENC * 4;

// ---------------- K1: fused prep, wave-shuffle scans (1 block, 512 thr, 4 barriers) ----------------
__global__ __launch_bounds__(512) void k_prep(const float* __restrict__ pts,
                                              int* __restrict__ cell_start,
                                              int* __restrict__ desc,
                                              float4* __restrict__ spts) {
    __shared__ int cnt_l[512];
    __shared__ int cur_l[512];
    __shared__ int wsum[8];
    const int t = threadIdx.x;
    const int lane = t & 63, w = t >> 6;
    cnt_l[t] = 0;
    __syncthreads();

    float xs[16], ys[16], zs[16];
    int   cids[16];
    #pragma unroll
    for (int k = 0; k < 16; ++k) {
        int i = t + k * 512;
        float x = pts[3 * i + 0], y = pts[3 * i + 1], z = pts[3 * i + 2];
        xs[k] = x; ys[k] = y; zs[k] = z;
        int cid = (cell_of(x) << 6) | (cell_of(y) << 3) | cell_of(z);
        cids[k] = cid;
        atomicAdd(&cnt_l[cid], 1);
    }
    __syncthreads();
    const int c = cnt_l[t];

    // wave-level inclusive scan of counts (cell scan)
    int v = c;
    #pragma unroll
    for (int off = 1; off < 64; off <<= 1) {
        int up = __shfl_up(v, off);
        if (lane >= off) v += up;
    }
    if (lane == 63) wsum[w] = v;

    // per-slab chunk scan: slab == wave (64 cells each) -> purely intra-wave
    const int nch = (c + 3) >> 2;
    int v2 = nch;
    #pragma unroll
    for (int off = 1; off < 64; off <<= 1) {
        int up = __shfl_up(v2, off);
        if (lane >= off) v2 += up;
    }
    const int rank = v2 - nch;
    __syncthreads();

    int woff = 0;
    #pragma unroll
    for (int i = 0; i < 8; ++i) woff += (i < w) ? wsum[i] : 0;
    const int excl = woff + v - c;
    cell_start[t] = excl;
    cur_l[t]      = excl;
    if (t == 511) cell_start[NCELLS] = woff + v;   // = N_PTS

    for (int i = t; i < GRID_MAIN; i += 512) desc[i] = -1;
    __syncthreads();   // desc fill + cur_l visible

    const int slab = w;                      // t>>6 == slab index
    for (int k = 0; k < nch; ++k) {
        int pos = rank + k;
        if (pos < NCH_SLAB) desc[slab + 8 * pos] = (t << 6) | k;
    }

    // scatter from registers via LDS cursors
    #pragma unroll
    for (int k = 0; k < 16; ++k) {
        int i = t + k * 512;
        int pos = atomicAdd(&cur_l[cids[k]], 1);
        spts[pos] = make_float4(xs[k], ys[k], zs[k], __int_as_float(i));
    }
}

// ---------------- K2: cs[pos][d] = (cos,sin) fp16, SORTED order; 8 pts/block ----------------
__global__ __launch_bounds__(NTHREAD) void k_encode(const float4* __restrict__ spts,
                                                    const float* __restrict__ A,
                                                    __half2* __restrict__ cs) {
    const int t  = threadIdx.x;
    const int p0 = blockIdx.x * 8;
    const float a0 = A[t], a1 = A[ENC + t], a2 = A[2 * ENC + t];
    #pragma unroll
    for (int k = 0; k < 8; ++k) {
        int p = p0 + k;
        if (p > N_PTS) break;
        if (p == N_PTS) {                 // dummy zero row for padded gathers
            cs[(size_t)p * ENC + t] = __floats2half2_rn(0.f, 0.f);
            break;
        }
        float4 P = spts[p];
        float qx = __fdiv_rn(P.x, RADIUS);
        float qy = __fdiv_rn(P.y, RADIUS);
        float qz = __fdiv_rn(P.z, RADIUS);
        float pa = fmaf(qz, a2, fmaf(qy, a1, qx * a0));
        float s, c;
        fast_sincos(pa, s, c);
        cs[(size_t)p * ENC + t] = __floats2half2_rn(c, s);
    }
}

// ---------------- K4: main — one 4-point chunk per block (R18 body, unchanged) ----------------
__global__ __launch_bounds__(NTHREAD) void k_main(const float4* __restrict__ spts,
                                                  const int* __restrict__ cell_start,
                                                  const int* __restrict__ desc_g,
                                                  const uint4* __restrict__ cs4,  // row = 96 uint4
                                                  float* __restrict__ out, int out_mode) {
    const int d = desc_g[blockIdx.x];
    if (d < 0) return;
    const int cell = d >> 6;
    const int kk   = d & 63;
    const int t = threadIdx.x, lane = t & 63, wv = t >> 6;
    const int g = t / 96, q = t - g * 96;               // group 0..3; dims 4q..4q+3

    __shared__ int    run_lo[9], run_hi[9];
    __shared__ float4 own_l[4];
    __shared__ int    ne;
    __shared__ __align__(16) unsigned int ent_g[4][96];   // entry = idx | mask<<16
    __shared__ uint4  comb_a[4][96];    // [point][q] — lane-consecutive, conflict-free
    __shared__ uint4  comb_b[4][96];
    __shared__ float  red2[4][96];
    __shared__ float  scale_l[4];

    const int o_lo = cell_start[cell];
    const int o_hi = cell_start[cell + 1];
    const int pbase = o_lo + (kk << 2);
    const int np = min(4, o_hi - pbase);

    // cell-level window: 9 z-runs
    const int cx = cell >> 6, cy = (cell >> 3) & 7, cz = cell & 7;
    if (t < 9) {
        int dx = t / 3 - 1, dy = t % 3 - 1;
        int cxx = cx + dx, cyy = cy + dy;
        int lo = 0, hi = 0;
        if (cxx >= 0 && cxx <= 7 && cyy >= 0 && cyy <= 7) {
            int basec = (cxx * 8 + cyy) * 8;
            int zlo = max(cz - 1, 0), zhi = min(cz + 1, 7);
            lo = cell_start[basec + zlo];
            hi = cell_start[basec + zhi + 1];
        }
        run_lo[t] = lo; run_hi[t] = hi;
    }
    if (t == 0) ne = 0;
    if (t < 4) {
        int idx = pbase + t;
        own_l[t] = (idx < o_hi) ? spts[idx] : make_float4(1e9f, 1e9f, 1e9f, 0.f);
    }
    __syncthreads();
    const float4 O0 = own_l[0], O1 = own_l[1], O2 = own_l[2], O3 = own_l[3];

    const double R2 = (double)0.12 * (double)0.12;
    const float R2_LO = 0.0144f - 1e-6f;
    const float R2_HI = 0.0144f + 1e-6f;
    const uint4* csq = cs4 + q;

    // ---- Phase 1: union scan, 4-bit membership mask (classification == R5-R18) ----
    for (int r = wv; r < 9; r += 6) {
        const int lo = run_lo[r], hi = run_hi[r];
        for (int jb = lo; jb < hi; jb += 64) {
            int j = jb + lane;
            unsigned mk = 0;
            if (j < hi) {
                float4 Pj = spts[j];
                #define TEST(O, BIT) { \
                    float fdx = Pj.x - O.x, fdy = Pj.y - O.y, fdz = Pj.z - O.z; \
                    float d2f = fmaf(fdx, fdx, fmaf(fdy, fdy, fdz * fdz)); \
                    if (d2f < R2_LO) mk |= (BIT); \
                    else if (d2f <= R2_HI) { \
                        double ddx = (double)Pj.x - (double)O.x; \
                        double ddy = (double)Pj.y - (double)O.y; \
                        double ddz = (double)Pj.z - (double)O.z; \
                        if (ddx * ddx + ddy * ddy + ddz * ddz < R2) mk |= (BIT); \
                    } }
                TEST(O0, 1u) TEST(O1, 2u) TEST(O2, 4u) TEST(O3, 8u)
                #undef TEST
            }
            unsigned long long mask = __ballot(mk != 0);
            if (mask) {
                int leader = __ffsll((long long)mask) - 1;
                int basep = 0;
                if (lane == leader) basep = atomicAdd(&ne, __popcll(mask));
                basep = __shfl(basep, leader);
                if (mk != 0) {
                    int pos = basep + __popcll(mask & ((1ull << lane) - 1ull));
                    if (pos < MAXU) ent_g[pos & 3][pos >> 2] = (unsigned)j | (mk << 16);
                }
            }
        }
    }
    __syncthreads();
    const int ne_p  = min(ne, MAXU);
    const int total = (ne_p + 15) & ~15;
    if (t < total - ne_p) {
        int pos = ne_p + t;
        ent_g[pos & 3][pos >> 2] = (unsigned)N_PTS;   // dummy row, mask 0
    }
    __syncthreads();
    const int P = total >> 2;            // entries per group (multiple of 4, <= 92)

    // ---- Phase 2: each row loaded ONCE, mask-fma'd into up to 4 points ----
    __half2 ax0[4], ax1[4], ax2[4], ax3[4];
    #pragma unroll
    for (int dd = 0; dd < 4; ++dd) {
        ax0[dd] = u2h(0u); ax1[dd] = u2h(0u); ax2[dd] = u2h(0u); ax3[dd] = u2h(0u);
    }
    for (int m = 0; m < P; m += 4) {
        uint4 ev = *(const uint4*)&ent_g[g][m];
        uint4 r0 = csq[(size_t)(ev.x & 0xFFFFu) * 96];
        uint4 r1 = csq[(size_t)(ev.y & 0xFFFFu) * 96];
        uint4 r2 = csq[(size_t)(ev.z & 0xFFFFu) * 96];
        uint4 r3 = csq[(size_t)(ev.w & 0xFFFFu) * 96];
        #define ACC4(R, MK) { \
            unsigned mk_ = (MK); \
            __half2 h0 = u2h((mk_ & 1u) ? 0x3C003C00u : 0u); \
            __half2 h1 = u2h((mk_ & 2u) ? 0x3C003C00u : 0u); \
            __half2 h2 = u2h((mk_ & 4u) ? 0x3C003C00u : 0u); \
            __half2 h3 = u2h((mk_ & 8u) ? 0x3C003C00u : 0u); \
            __half2 rx = u2h(R.x), ry = u2h(R.y), rz = u2h(R.z), rw = u2h(R.w); \
            ax0[0] = __hfma2(rx, h0, ax0[0]); ax0[1] = __hfma2(ry, h0, ax0[1]); \
            ax0[2] = __hfma2(rz, h0, ax0[2]); ax0[3] = __hfma2(rw, h0, ax0[3]); \
            ax1[0] = __hfma2(rx, h1, ax1[0]); ax1[1] = __hfma2(ry, h1, ax1[1]); \
            ax1[2] = __hfma2(rz, h1, ax1[2]); ax1[3] = __hfma2(rw, h1, ax1[3]); \
            ax2[0] = __hfma2(rx, h2, ax2[0]); ax2[1] = __hfma2(ry, h2, ax2[1]); \
            ax2[2] = __hfma2(rz, h2, ax2[2]); ax2[3] = __hfma2(rw, h2, ax2[3]); \
            ax3[0] = __hfma2(rx, h3, ax3[0]); ax3[1] = __hfma2(ry, h3, ax3[1]); \
            ax3[2] = __hfma2(rz, h3, ax3[2]); ax3[3] = __hfma2(rw, h3, ax3[3]); }
        ACC4(r0, ev.x >> 16) ACC4(r1, ev.y >> 16) ACC4(r2, ev.z >> 16) ACC4(r3, ev.w >> 16)
        #undef ACC4
    }

    // ---- two-stage combine (transposed conflict-free buffers) ----
    #define PACK4(A) make_uint4(h2u(A[0]), h2u(A[1]), h2u(A[2]), h2u(A[3]))
    #define ADDU(A, V) { A[0] = __hadd2(A[0], u2h(V.x)); A[1] = __hadd2(A[1], u2h(V.y)); \
                         A[2] = __hadd2(A[2], u2h(V.z)); A[3] = __hadd2(A[3], u2h(V.w)); }
    if (g == 1) { comb_a[0][q] = PACK4(ax0); comb_a[1][q] = PACK4(ax1);
                  comb_a[2][q] = PACK4(ax2); comb_a[3][q] = PACK4(ax3); }
    else if (g == 3) { comb_b[0][q] = PACK4(ax0); comb_b[1][q] = PACK4(ax1);
                       comb_b[2][q] = PACK4(ax2); comb_b[3][q] = PACK4(ax3); }
    __syncthreads();
    if (g == 0) { uint4 v0 = comb_a[0][q], v1 = comb_a[1][q], v2 = comb_a[2][q], v3 = comb_a[3][q];
                  ADDU(ax0, v0) ADDU(ax1, v1) ADDU(ax2, v2) ADDU(ax3, v3) }
    else if (g == 2) { uint4 v0 = comb_b[0][q], v1 = comb_b[1][q], v2 = comb_b[2][q], v3 = comb_b[3][q];
                       ADDU(ax0, v0) ADDU(ax1, v1) ADDU(ax2, v2) ADDU(ax3, v3) }
    __syncthreads();
    if (g == 2) { comb_a[0][q] = PACK4(ax0); comb_a[1][q] = PACK4(ax1);
                  comb_a[2][q] = PACK4(ax2); comb_a[3][q] = PACK4(ax3); }
    __syncthreads();
    if (g == 0) {
        uint4 v0 = comb_a[0][q], v1 = comb_a[1][q], v2 = comb_a[2][q], v3 = comb_a[3][q];
        ADDU(ax0, v0) ADDU(ax1, v1) ADDU(ax2, v2) ADDU(ax3, v3)
        #define NORM_P(AC, PP) { float m2 = 0.f; \
            _Pragma("unroll") for (int dd = 0; dd < 4; ++dd) { \
                float2 f = __half22float2(AC[dd]); \
                m2 = fmaf(f.x, f.x, fmaf(f.y, f.y, m2)); } \
            red2[PP][q] = m2; }
        NORM_P(ax0, 0) NORM_P(ax1, 1) NORM_P(ax2, 2) NORM_P(ax3, 3)
        #undef NORM_P
    }
    #undef PACK4
    #undef ADDU
    __syncthreads();
    if (t < 256) {
        int w = t >> 6, l = t & 63;
        float v = red2[w][l] + (l < 32 ? red2[w][64 + l] : 0.f);
        #pragma unroll
        for (int off = 32; off > 0; off >>= 1) v += __shfl_down(v, off);
        if (l == 0) scale_l[w] = sqrtf(384.0f / v);
    }
    __syncthreads();
    if (g == 0) {
        #define STORE_P(AC, PP) if ((PP) < np) { \
            const float scl = scale_l[PP]; \
            uint4 ov = csq[(size_t)(pbase + (PP)) * 96]; \
            float2 o0 = __half22float2(u2h(ov.x)), o1 = __half22float2(u2h(ov.y)); \
            float2 o2 = __half22float2(u2h(ov.z)), o3 = __half22float2(u2h(ov.w)); \
            float2 g0v = __half22float2(AC[0]), g1v = __half22float2(AC[1]); \
            float2 g2v = __half22float2(AC[2]), g3v = __half22float2(AC[3]); \
            float re0 = (g0v.x * o0.x + g0v.y * o0.y) * scl, im0 = (g0v.y * o0.x - g0v.x * o0.y) * scl; \
            float re1 = (g1v.x * o1.x + g1v.y * o1.y) * scl, im1 = (g1v.y * o1.x - g1v.x * o1.y) * scl; \
            float re2 = (g2v.x * o2.x + g2v.y * o2.y) * scl, im2 = (g2v.y * o2.x - g2v.x * o2.y) * scl; \
            float re3 = (g3v.x * o3.x + g3v.y * o3.y) * scl, im3 = (g3v.y * o3.x - g3v.x * o3.y) * scl; \
            const int o = __float_as_int(own_l[PP].w); \
            if (out_mode == 0) { \
                ((float4*)out)[(size_t)o * 96 + q] = make_float4(re0, re1, re2, re3); \
            } else { \
                ((float4*)out)[(size_t)o * 192 + 2 * q + 0] = make_float4(re0, im0, re1, im1); \
                ((float4*)out)[(size_t)o * 192 + 2 * q + 1] = make_float4(re2, im2, re3, im3); \
            } }
        STORE_P(ax0, 0) STORE_P(ax1, 1) STORE_P(ax2, 2) STORE_P(ax3, 3)
        #undef STORE_P
    }
}

// ---------------- last-resort all-pairs (ws too small; effectively dead) ----------------
__global__ __launch_bounds__(NTHREAD) void vecKM_allpairs(const float* __restrict__ pts,
                                                          const float* __restrict__ A,
                                                          float* __restrict__ out, int out_mode) {
    const int i = blockIdx.x;
    const int t = threadIdx.x;
    __shared__ float nb_x[512], nb_y[512], nb_z[512];
    __shared__ int nb_cnt;
    __shared__ float red[8];
    if (t == 0) nb_cnt = 0;
    __syncthreads();
    const float xi = pts[3 * i + 0], yi = pts[3 * i + 1], zi = pts[3 * i + 2];
    const double dxi = xi, dyi = yi, dzi = zi;
    const double R2 = (double)0.12 * (double)0.12;
    const float R2_LO = 0.0144f - 1e-6f, R2_HI = 0.0144f + 1e-6f;
    const int lane = t & 63;
    for (int jb = 0; jb < N_PTS; jb += NTHREAD) {
        const int j = jb + t;
        bool isnb = false;
        float xj = 0.f, yj = 0.f, zj = 0.f;
        if (j < N_PTS) {
            xj = pts[3 * j + 0]; yj = pts[3 * j + 1]; zj = pts[3 * j + 2];
            float fdx = xj - xi, fdy = yj - yi, fdz = zj - zi;
            float d2f = fmaf(fdx, fdx, fmaf(fdy, fdy, fdz * fdz));
            if (d2f < R2_LO) isnb = true;
            else if (d2f <= R2_HI) {
                double dx = (double)xj - dxi, dy = (double)yj - dyi, dz = (double)zj - dzi;
                isnb = (dx * dx + dy * dy + dz * dz) < R2;
            }
        }
        unsigned long long mask = __ballot(isnb);
        if (mask) {
            int leader = __ffsll((long long)mask) - 1;
            int basep = 0;
            if (lane == leader) basep = atomicAdd(&nb_cnt, __popcll(mask));
            basep = __shfl(basep, leader);
            if (isnb) {
                int pos = basep + __popcll(mask & ((1ull << lane) - 1ull));
                if (pos < 512) {
                    nb_x[pos] = (xj - xi) * (1.0f / 0.12f);
                    nb_y[pos] = (yj - yi) * (1.0f / 0.12f);
                    nb_z[pos] = (zj - zi) * (1.0f / 0.12f);
                }
            }
        }
    }
    __syncthreads();
    const int nn = min(nb_cnt, 512);
    const float a0 = A[t], a1 = A[ENC + t], a2 = A[2 * ENC + t];
    float gr = 0.f, gi = 0.f;
    #pragma unroll 4
    for (int m = 0; m < nn; ++m) {
        float pa = fmaf(nb_z[m], a2, fmaf(nb_y[m], a1, nb_x[m] * a0));
        float sv, cv;
        fast_sincos(pa, sv, cv);
        gr += cv; gi += sv;
    }
    float m2 = fmaf(gr, gr, gi * gi);
    #pragma unroll
    for (int off = 32; off > 0; off >>= 1) m2 += __shfl_down(m2, off);
    const int wid = t >> 6;
    if (lane == 0) red[wid] = m2;
    __syncthreads();
    if (t == 0) {
        float tot = 0.f;
        for (int w = 0; w < NTHREAD / 64; ++w) tot += red[w];
        red[7] = tot;
    }
    __syncthreads();
    const float scale = sqrtf(384.0f / red[7]);
    const float re = gr * scale, im = gi * scale;
    if (out_mode == 0) out[i * ENC + t] = re;
    else ((float2*)out)[i * ENC + t] = make_float2(re, im);
}

extern "C" void kernel_launch(void* const* d_in, const int* in_sizes, int n_in,
                              void* d_out, int out_size, void* d_ws, size_t ws_size,
                              hipStream_t stream) {
    const float* pts = (const float*)d_in[0];
    const float* A   = (const float*)d_in[1];
    float* out = (float*)d_out;
    const int out_mode = (out_size >= 2 * N_PTS * ENC) ? 1 : 0;

    if (ws_size >= WS_FULL_B) {
        int*     cell_start = (int*)d_ws + OFF_CSTART_I;
        int*     desc       = (int*)d_ws + OFF_DESC_I;
        float4*  spts       = (float4*)((char*)d_ws + OFF_SPTS_B);
        __half2* cs         = (__half2*)((char*)d_ws + OFF_CS_B);

        k_prep<<<1, 512, 0, stream>>>(pts, cell_start, desc, spts);
        k_encode<<<(N_PTS / 8) + 1, NTHREAD, 0, stream>>>(spts, A, cs);
        k_main<<<GRID_MAIN, NTHREAD, 0, stream>>>(spts, cell_start, desc,
                                                  (const uint4*)cs, out, out_mode);
    } else {
        vecKM_allpairs<<<N_PTS, NTHREAD, 0, stream>>>(pts, A, out, out_mode);
    }
}